// Round 5
// baseline (116.831 us; speedup 1.0000x reference)
//
#include <hip/hip_runtime.h>
#include <hip/hip_bf16.h>

#define EPS 1e-12f

typedef __bf16 bf16x8 __attribute__((ext_vector_type(8)));
typedef __bf16 bf16x4 __attribute__((ext_vector_type(4)));
typedef float  f32x4  __attribute__((ext_vector_type(4)));

// Problem constants: B=16, N=1024, M=12, F_atom=128, F_bond=32, F_out=128

// ---------------------------------------------------------------------------
// K1 blocks 0..255 : bond-norm chain -> p[row], 4 threads per row, NT loads.
//    p = (prod_m x_m) / d^12, d = max(sum_m x_m, EPS), x_m = 1/||bond_m||^2
// K1 blocks 256..259 : W (128x128 f32 [k][j]) -> Wt bf16 [j][k]
// ---------------------------------------------------------------------------
__global__ __launch_bounds__(256) void k_bond(const float* __restrict__ bond,
                                              const float* __restrict__ W,
                                              float* __restrict__ p_out,
                                              __bf16* __restrict__ Wt) {
    const int t = threadIdx.x;
    if (blockIdx.x < 256) {
        const int gtid = blockIdx.x * 256 + t;
        const int row  = gtid >> 2;      // 0..16383
        const int q    = gtid & 3;       // m = 3q..3q+2
        const float* base = bond + (size_t)row * 384 + q * 96;

        float x[3];
#pragma unroll
        for (int mm = 0; mm < 3; ++mm) {
            float s = 0.f;
#pragma unroll
            for (int j = 0; j < 8; ++j) {
                f32x4 v = __builtin_nontemporal_load((const f32x4*)(base + mm * 32 + j * 4));
                s = fmaf(v.x, v.x, s);
                s = fmaf(v.y, v.y, s);
                s = fmaf(v.z, v.z, s);
                s = fmaf(v.w, v.w, s);
            }
            x[mm] = 1.0f / s;            // (sqrt(s))^-2 == 1/s
        }
        float sum  = x[0] + x[1] + x[2];
        float prod = x[0] * x[1] * x[2];
        sum  += __shfl_xor(sum, 1);  prod *= __shfl_xor(prod, 1);
        sum  += __shfl_xor(sum, 2);  prod *= __shfl_xor(prod, 2);
        if (q == 0) {
            float d   = fmaxf(sum, EPS);
            float d2  = d * d, d3 = d2 * d, d6 = d3 * d3;
            p_out[row] = prod / (d6 * d6);   // prod(x/d) = prod(x)/d^12
        }
    } else {
        const int base = (blockIdx.x - 256) * 4096;
#pragma unroll
        for (int i = 0; i < 16; ++i) {
            int idx = base + t + 256 * i;
            int k = idx >> 7, j = idx & 127;
            Wt[j * 128 + k] = (__bf16)W[idx];
        }
    }
}

// ---------------------------------------------------------------------------
// K2: scale applied in EPILOGUE (diag(s)U)W == diag(s)(UW) — so the p-based
// scale reduction overlaps the in-flight gather loads.
// 32 rows/block, 256 threads (4 waves), per-wave 16x64 MFMA tile.
// ---------------------------------------------------------------------------
__global__ __launch_bounds__(256) void k_main(const float* __restrict__ atom,
                                              const int* __restrict__ adj,
                                              const float* __restrict__ p,
                                              const __bf16* __restrict__ Wt,
                                              const float* __restrict__ bias,
                                              float* __restrict__ out) {
    __shared__ __bf16 uA[32][136];   // stride 136: 8B-aligned rows, 2-way banking (free)
    __shared__ float  sScale[32] __attribute__((aligned(16)));
    __shared__ int    sAdj[32 * 12];
    __shared__ float  red[4];

    const int t = threadIdx.x;
    const int rowbase = blockIdx.x * 32;   // 1024 % 32 == 0 -> block within one batch
    const int b = rowbase >> 10;
    const int nlo = rowbase & 1023;

    // ---- issue p loads FIRST (no dependencies; L2-hot) ----
    const int n0 = t * 4;                  // local n, covers [0,1024)
    f32x4 cs = {0.f, 0.f, 0.f, 0.f};
    f32x4 pv[16];
#pragma unroll
    for (int bb = 0; bb < 16; ++bb) pv[bb] = *(const f32x4*)(p + bb * 1024 + n0);

    // ---- stage adjacency, then issue gather loads ----
    for (int idx = t; idx < 32 * 12; idx += 256) sAdj[idx] = adj[rowbase * 12 + idx];
    __syncthreads();

    const int jc = (t & 31) * 4;           // 4 cols/thread
    const int rg = t >> 5;                 // 8 rows in parallel
    const float* atomB = atom + (size_t)b * (1024 * 128);
    f32x4 own[4], accn[4];
#pragma unroll
    for (int i = 0; i < 4; ++i) {
        const int r = rg + i * 8;
        f32x4 a = {0.f, 0.f, 0.f, 0.f};
#pragma unroll
        for (int m = 0; m < 12; ++m) {
            int idx = sAdj[r * 12 + m];
            a += *(const f32x4*)(atomB + (size_t)idx * 128 + jc);
        }
        accn[i] = a;
        own[i]  = *(const f32x4*)(atomB + (size_t)(nlo + r) * 128 + jc);
    }

    // ---- Phase 0: scale (redundant per block; uses only p) ----
    // r[n] = max(sum_bb p[bb,n], EPS) / p[b,n];  scale = r / max(sum_n r, EPS)
#pragma unroll
    for (int bb = 0; bb < 16; ++bb) cs += pv[bb];
    f32x4 pb = pv[b];
    f32x4 r4;
    r4.x = fmaxf(cs.x, EPS) / pb.x;
    r4.y = fmaxf(cs.y, EPS) / pb.y;
    r4.z = fmaxf(cs.z, EPS) / pb.z;
    r4.w = fmaxf(cs.w, EPS) / pb.w;
    float S_part = r4.x + r4.y + r4.z + r4.w;
#pragma unroll
    for (int off = 32; off >= 1; off >>= 1) S_part += __shfl_xor(S_part, off);
    if ((t & 63) == 0) red[t >> 6] = S_part;

    // ---- Phase 1: unscaled u -> bf16 LDS (needs gather loads) ----
#pragma unroll
    for (int i = 0; i < 4; ++i) {
        const int r = rg + i * 8;
        f32x4 u = own[i] + accn[i] * (1.0f / 12.0f);
        bf16x4 ub;
        ub.x = (__bf16)u.x; ub.y = (__bf16)u.y; ub.z = (__bf16)u.z; ub.w = (__bf16)u.w;
        *(bf16x4*)&uA[r][jc] = ub;
    }
    __syncthreads();   // red + uA ready

    const float invS = 1.0f / fmaxf(red[0] + red[1] + red[2] + red[3], EPS);
    if (n0 >= nlo && n0 < nlo + 32) *(f32x4*)&sScale[n0 - nlo] = r4 * invS;

    // ---- Phase 2: per-wave 16x64 tile via mfma_f32_16x16x32_bf16 ----
    const int wave = t >> 6, lane = t & 63;
    const int r0 = (wave >> 1) * 16;
    const int c0 = (wave & 1) * 64;
    const int quad = lane >> 4, lrow = lane & 15;

    bf16x8 aF[4];
#pragma unroll
    for (int kc = 0; kc < 4; ++kc)
        aF[kc] = *(const bf16x8*)&uA[r0 + lrow][kc * 32 + quad * 8];

    f32x4 acc[4];
#pragma unroll
    for (int nt = 0; nt < 4; ++nt) acc[nt] = (f32x4){0.f, 0.f, 0.f, 0.f};

#pragma unroll
    for (int nt = 0; nt < 4; ++nt) {
        const int col = c0 + nt * 16 + lrow;
        const __bf16* wb = Wt + col * 128 + quad * 8;
#pragma unroll
        for (int kc = 0; kc < 4; ++kc) {
            bf16x8 bF = *(const bf16x8*)(wb + kc * 32);
            acc[nt] = __builtin_amdgcn_mfma_f32_16x16x32_bf16(aF[kc], bF, acc[nt], 0, 0, 0);
        }
    }
    __syncthreads();   // sScale ready (cheap; waves already barrier-aligned here)

    // ---- Epilogue: out = relu(scale[r]*acc + bias); C/D col=lane&15,row=quad*4+i ----
#pragma unroll
    for (int nt = 0; nt < 4; ++nt) {
        const int col = c0 + nt * 16 + lrow;
        const float bv = bias[col];
#pragma unroll
        for (int i = 0; i < 4; ++i) {
            const int r = r0 + quad * 4 + i;
            float v = fmaxf(fmaf(sScale[r], acc[nt][i], bv), 0.f);
            __builtin_nontemporal_store(v, &out[(size_t)(rowbase + r) * 128 + col]);
        }
    }
}

// ---------------------------------------------------------------------------
extern "C" void kernel_launch(void* const* d_in, const int* in_sizes, int n_in,
                              void* d_out, int out_size, void* d_ws, size_t ws_size,
                              hipStream_t stream) {
    const float* atom = (const float*)d_in[0];
    const float* bond = (const float*)d_in[1];
    const int*   adj  = (const int*)d_in[2];
    const float* W    = (const float*)d_in[3];
    const float* bias = (const float*)d_in[4];
    float* out = (float*)d_out;

    char* ws = (char*)d_ws;
    float*  p  = (float*)ws;               // 16384 f32 = 64 KB
    __bf16* Wt = (__bf16*)(ws + 65536);    // 16384 bf16 = 32 KB

    hipLaunchKernelGGL(k_bond, dim3(260), dim3(256), 0, stream, bond, W, p, Wt);
    hipLaunchKernelGGL(k_main, dim3(512), dim3(256), 0, stream, atom, adj, p, Wt, bias, out);
}

// Round 6
// 105.869 us; speedup vs baseline: 1.1035x; 1.1035x over previous
//
#include <hip/hip_runtime.h>
#include <hip/hip_bf16.h>

#define EPS 1e-12f

typedef __bf16 bf16x8 __attribute__((ext_vector_type(8)));
typedef __bf16 bf16x4 __attribute__((ext_vector_type(4)));
typedef float  f32x4  __attribute__((ext_vector_type(4)));

// Problem constants: B=16, N=1024, M=12, F_atom=128, F_bond=32, F_out=128

// ---------------------------------------------------------------------------
// K1 blocks 0..255 : bond-norm chain -> p[row], 4 threads per row, NT loads.
//    p = (prod_m x_m) / d^12, d = max(sum_m x_m, EPS), x_m = 1/||bond_m||^2
// K1 blocks 256..259 : W (128x128 f32 [k][j]) -> Wt bf16 [j][k]
// ---------------------------------------------------------------------------
__global__ __launch_bounds__(256) void k_bond(const float* __restrict__ bond,
                                              const float* __restrict__ W,
                                              float* __restrict__ p_out,
                                              __bf16* __restrict__ Wt) {
    const int t = threadIdx.x;
    if (blockIdx.x < 256) {
        const int gtid = blockIdx.x * 256 + t;
        const int row  = gtid >> 2;      // 0..16383
        const int q    = gtid & 3;       // m = 3q..3q+2
        const float* base = bond + (size_t)row * 384 + q * 96;

        float x[3];
#pragma unroll
        for (int mm = 0; mm < 3; ++mm) {
            float s = 0.f;
#pragma unroll
            for (int j = 0; j < 8; ++j) {
                f32x4 v = __builtin_nontemporal_load((const f32x4*)(base + mm * 32 + j * 4));
                s = fmaf(v.x, v.x, s);
                s = fmaf(v.y, v.y, s);
                s = fmaf(v.z, v.z, s);
                s = fmaf(v.w, v.w, s);
            }
            x[mm] = 1.0f / s;            // (sqrt(s))^-2 == 1/s
        }
        float sum  = x[0] + x[1] + x[2];
        float prod = x[0] * x[1] * x[2];
        sum  += __shfl_xor(sum, 1);  prod *= __shfl_xor(prod, 1);
        sum  += __shfl_xor(sum, 2);  prod *= __shfl_xor(prod, 2);
        if (q == 0) {
            float d   = fmaxf(sum, EPS);
            float d2  = d * d, d3 = d2 * d, d6 = d3 * d3;
            p_out[row] = prod / (d6 * d6);   // prod(x/d) = prod(x)/d^12
        }
    } else {
        const int base = (blockIdx.x - 256) * 4096;
#pragma unroll
        for (int i = 0; i < 16; ++i) {
            int idx = base + t + 256 * i;
            int k = idx >> 7, j = idx & 127;
            Wt[j * 128 + k] = (__bf16)W[idx];
        }
    }
}

// ---------------------------------------------------------------------------
// K2: round-3 structure (scale in phase 1, two barriers, low VGPR pressure)
// + float4 gather. 32 rows/block, 256 threads, per-wave 16x64 MFMA tile.
// ---------------------------------------------------------------------------
__global__ __launch_bounds__(256) void k_main(const float* __restrict__ atom,
                                              const int* __restrict__ adj,
                                              const float* __restrict__ p,
                                              const __bf16* __restrict__ Wt,
                                              const float* __restrict__ bias,
                                              float* __restrict__ out) {
    __shared__ __bf16 uA[32][136];   // stride 136: 8B-aligned rows, 2-way banking (free)
    __shared__ float  sScale[32] __attribute__((aligned(16)));
    __shared__ int    sAdj[32 * 12];
    __shared__ float  red[4];

    const int t = threadIdx.x;
    const int rowbase = blockIdx.x * 32;   // 1024 % 32 == 0 -> block within one batch
    const int b = rowbase >> 10;
    const int nlo = rowbase & 1023;

    for (int idx = t; idx < 32 * 12; idx += 256) sAdj[idx] = adj[rowbase * 12 + idx];

    // ---- Phase 0: scale (vectorized, immediate accumulation — low reg pressure) ----
    // r[n] = max(sum_bb p[bb,n], EPS) / p[b,n];  scale = r / max(sum_n r, EPS)
    const int n0 = t * 4;                  // local n in [0,1024)
    f32x4 cs = {0.f, 0.f, 0.f, 0.f};
#pragma unroll
    for (int bb = 0; bb < 16; ++bb) cs += *(const f32x4*)(p + bb * 1024 + n0);
    f32x4 pb = *(const f32x4*)(p + b * 1024 + n0);   // L2-hot re-read
    f32x4 r4;
    r4.x = fmaxf(cs.x, EPS) / pb.x;
    r4.y = fmaxf(cs.y, EPS) / pb.y;
    r4.z = fmaxf(cs.z, EPS) / pb.z;
    r4.w = fmaxf(cs.w, EPS) / pb.w;
    float S_part = r4.x + r4.y + r4.z + r4.w;
#pragma unroll
    for (int off = 32; off >= 1; off >>= 1) S_part += __shfl_xor(S_part, off);
    if ((t & 63) == 0) red[t >> 6] = S_part;
    __syncthreads();
    const float invS = 1.0f / fmaxf(red[0] + red[1] + red[2] + red[3], EPS);
    if (n0 >= nlo && n0 < nlo + 32) *(f32x4*)&sScale[n0 - nlo] = r4 * invS;
    __syncthreads();

    // ---- Phase 1: float4 gather; u = (own + accn/12) * scale -> bf16 LDS ----
    {
        const int jc = (t & 31) * 4;       // 4 cols/thread
        const int rg = t >> 5;             // 8 rows in parallel
        const float* atomB = atom + (size_t)b * (1024 * 128);
#pragma unroll
        for (int i = 0; i < 4; ++i) {
            const int r = rg + i * 8;
            f32x4 a = {0.f, 0.f, 0.f, 0.f};
#pragma unroll
            for (int m = 0; m < 12; ++m) {
                int idx = sAdj[r * 12 + m];
                a += *(const f32x4*)(atomB + (size_t)idx * 128 + jc);
            }
            f32x4 own = *(const f32x4*)(atomB + (size_t)(nlo + r) * 128 + jc);
            f32x4 u = (own + a * (1.0f / 12.0f)) * sScale[r];
            bf16x4 ub;
            ub.x = (__bf16)u.x; ub.y = (__bf16)u.y; ub.z = (__bf16)u.z; ub.w = (__bf16)u.w;
            *(bf16x4*)&uA[r][jc] = ub;
        }
    }
    __syncthreads();

    // ---- Phase 2: per-wave 16x64 tile via mfma_f32_16x16x32_bf16 ----
    const int wave = t >> 6, lane = t & 63;
    const int r0 = (wave >> 1) * 16;
    const int c0 = (wave & 1) * 64;
    const int quad = lane >> 4, lrow = lane & 15;

    bf16x8 aF[4];
#pragma unroll
    for (int kc = 0; kc < 4; ++kc)
        aF[kc] = *(const bf16x8*)&uA[r0 + lrow][kc * 32 + quad * 8];

    f32x4 acc[4];
#pragma unroll
    for (int nt = 0; nt < 4; ++nt) acc[nt] = (f32x4){0.f, 0.f, 0.f, 0.f};

#pragma unroll
    for (int nt = 0; nt < 4; ++nt) {
        const int col = c0 + nt * 16 + lrow;
        const __bf16* wb = Wt + col * 128 + quad * 8;
#pragma unroll
        for (int kc = 0; kc < 4; ++kc) {
            bf16x8 bF = *(const bf16x8*)(wb + kc * 32);
            acc[nt] = __builtin_amdgcn_mfma_f32_16x16x32_bf16(aF[kc], bF, acc[nt], 0, 0, 0);
        }
    }

    // ---- Epilogue: C/D layout col=lane&15, row=quad*4+i; NT stores ----
#pragma unroll
    for (int nt = 0; nt < 4; ++nt) {
        const int col = c0 + nt * 16 + lrow;
        const float bv = bias[col];
#pragma unroll
        for (int i = 0; i < 4; ++i) {
            const int r = r0 + quad * 4 + i;
            float v = fmaxf(acc[nt][i] + bv, 0.f);
            __builtin_nontemporal_store(v, &out[(size_t)(rowbase + r) * 128 + col]);
        }
    }
}

// ---------------------------------------------------------------------------
extern "C" void kernel_launch(void* const* d_in, const int* in_sizes, int n_in,
                              void* d_out, int out_size, void* d_ws, size_t ws_size,
                              hipStream_t stream) {
    const float* atom = (const float*)d_in[0];
    const float* bond = (const float*)d_in[1];
    const int*   adj  = (const int*)d_in[2];
    const float* W    = (const float*)d_in[3];
    const float* bias = (const float*)d_in[4];
    float* out = (float*)d_out;

    char* ws = (char*)d_ws;
    float*  p  = (float*)ws;               // 16384 f32 = 64 KB
    __bf16* Wt = (__bf16*)(ws + 65536);    // 16384 bf16 = 32 KB

    hipLaunchKernelGGL(k_bond, dim3(260), dim3(256), 0, stream, bond, W, p, Wt);
    hipLaunchKernelGGL(k_main, dim3(512), dim3(256), 0, stream, atom, adj, p, Wt, bias, out);
}

// Round 7
// 102.084 us; speedup vs baseline: 1.1445x; 1.0371x over previous
//
#include <hip/hip_runtime.h>
#include <hip/hip_bf16.h>

#define EPS 1e-12f

typedef __bf16 bf16x8 __attribute__((ext_vector_type(8)));
typedef __bf16 bf16x4 __attribute__((ext_vector_type(4)));
typedef float  f32x4  __attribute__((ext_vector_type(4)));

// Problem constants: B=16, N=1024, M=12, F_atom=128, F_bond=32, F_out=128

// ---------------------------------------------------------------------------
// K1 blocks 0..255 : bond-norm chain -> p[row], 4 threads per row, NT loads.
//    p = (prod_m x_m) / d^12, d = max(sum_m x_m, EPS), x_m = 1/||bond_m||^2
// K1 blocks 256..259 : W (128x128 f32 [k][j]) -> Wt bf16 [j][k]
// ---------------------------------------------------------------------------
__global__ __launch_bounds__(256) void k_bond(const float* __restrict__ bond,
                                              const float* __restrict__ W,
                                              float* __restrict__ p_out,
                                              __bf16* __restrict__ Wt) {
    const int t = threadIdx.x;
    if (blockIdx.x < 256) {
        const int gtid = blockIdx.x * 256 + t;
        const int row  = gtid >> 2;      // 0..16383
        const int q    = gtid & 3;       // m = 3q..3q+2
        const float* base = bond + (size_t)row * 384 + q * 96;

        float x[3];
#pragma unroll
        for (int mm = 0; mm < 3; ++mm) {
            float s = 0.f;
#pragma unroll
            for (int j = 0; j < 8; ++j) {
                f32x4 v = __builtin_nontemporal_load((const f32x4*)(base + mm * 32 + j * 4));
                s = fmaf(v.x, v.x, s);
                s = fmaf(v.y, v.y, s);
                s = fmaf(v.z, v.z, s);
                s = fmaf(v.w, v.w, s);
            }
            x[mm] = 1.0f / s;            // (sqrt(s))^-2 == 1/s
        }
        float sum  = x[0] + x[1] + x[2];
        float prod = x[0] * x[1] * x[2];
        sum  += __shfl_xor(sum, 1);  prod *= __shfl_xor(prod, 1);
        sum  += __shfl_xor(sum, 2);  prod *= __shfl_xor(prod, 2);
        if (q == 0) {
            float d   = fmaxf(sum, EPS);
            float d2  = d * d, d3 = d2 * d, d6 = d3 * d3;
            p_out[row] = prod / (d6 * d6);   // prod(x/d) = prod(x)/d^12
        }
    } else {
        const int base = (blockIdx.x - 256) * 4096;
#pragma unroll
        for (int i = 0; i < 16; ++i) {
            int idx = base + t + 256 * i;
            int k = idx >> 7, j = idx & 127;
            Wt[j * 128 + k] = (__bf16)W[idx];
        }
    }
}

// ---------------------------------------------------------------------------
// K2: round-6 structure + XCD-aware block swizzle: all 32 blocks of a batch
// share blk%8 (one XCD) -> per-XCD gather working set = 2 atom slices (1 MB),
// L2-resident, instead of all 16 (8 MB, L3-bound).
// ---------------------------------------------------------------------------
__global__ __launch_bounds__(256) void k_main(const float* __restrict__ atom,
                                              const int* __restrict__ adj,
                                              const float* __restrict__ p,
                                              const __bf16* __restrict__ Wt,
                                              const float* __restrict__ bias,
                                              float* __restrict__ out) {
    __shared__ __bf16 uA[32][136];   // stride 136: 8B-aligned rows, 2-way banking (free)
    __shared__ float  sScale[32] __attribute__((aligned(16)));
    __shared__ int    sAdj[32 * 12];
    __shared__ float  red[4];

    const int t = threadIdx.x;
    // XCD swizzle: batch = (blk&7)+8*(blk>=256), slot = (blk>>3)&31
    const int blk = blockIdx.x;
    const int b    = (blk & 7) | ((blk >> 8) << 3);
    const int nlo  = ((blk >> 3) & 31) * 32;
    const int rowbase = b * 1024 + nlo;

    for (int idx = t; idx < 32 * 12; idx += 256) sAdj[idx] = adj[rowbase * 12 + idx];

    // ---- Phase 0: scale (vectorized, immediate accumulation) ----
    // r[n] = max(sum_bb p[bb,n], EPS) / p[b,n];  scale = r / max(sum_n r, EPS)
    const int n0 = t * 4;                  // local n in [0,1024)
    f32x4 cs = {0.f, 0.f, 0.f, 0.f};
#pragma unroll
    for (int bb = 0; bb < 16; ++bb) cs += *(const f32x4*)(p + bb * 1024 + n0);
    f32x4 pb = *(const f32x4*)(p + b * 1024 + n0);   // L2-hot re-read
    f32x4 r4;
    r4.x = fmaxf(cs.x, EPS) / pb.x;
    r4.y = fmaxf(cs.y, EPS) / pb.y;
    r4.z = fmaxf(cs.z, EPS) / pb.z;
    r4.w = fmaxf(cs.w, EPS) / pb.w;
    float S_part = r4.x + r4.y + r4.z + r4.w;
#pragma unroll
    for (int off = 32; off >= 1; off >>= 1) S_part += __shfl_xor(S_part, off);
    if ((t & 63) == 0) red[t >> 6] = S_part;
    __syncthreads();
    const float invS = 1.0f / fmaxf(red[0] + red[1] + red[2] + red[3], EPS);
    if (n0 >= nlo && n0 < nlo + 32) *(f32x4*)&sScale[n0 - nlo] = r4 * invS;
    __syncthreads();

    // ---- Phase 1: float4 gather; u = (own + accn/12) * scale -> bf16 LDS ----
    {
        const int jc = (t & 31) * 4;       // 4 cols/thread
        const int rg = t >> 5;             // 8 rows in parallel
        const float* atomB = atom + (size_t)b * (1024 * 128);
#pragma unroll
        for (int i = 0; i < 4; ++i) {
            const int r = rg + i * 8;
            f32x4 a = {0.f, 0.f, 0.f, 0.f};
#pragma unroll
            for (int m = 0; m < 12; ++m) {
                int idx = sAdj[r * 12 + m];
                a += *(const f32x4*)(atomB + (size_t)idx * 128 + jc);
            }
            f32x4 own = *(const f32x4*)(atomB + (size_t)(nlo + r) * 128 + jc);
            f32x4 u = (own + a * (1.0f / 12.0f)) * sScale[r];
            bf16x4 ub;
            ub.x = (__bf16)u.x; ub.y = (__bf16)u.y; ub.z = (__bf16)u.z; ub.w = (__bf16)u.w;
            *(bf16x4*)&uA[r][jc] = ub;
        }
    }
    __syncthreads();

    // ---- Phase 2: per-wave 16x64 tile via mfma_f32_16x16x32_bf16 ----
    const int wave = t >> 6, lane = t & 63;
    const int r0 = (wave >> 1) * 16;
    const int c0 = (wave & 1) * 64;
    const int quad = lane >> 4, lrow = lane & 15;

    bf16x8 aF[4];
#pragma unroll
    for (int kc = 0; kc < 4; ++kc)
        aF[kc] = *(const bf16x8*)&uA[r0 + lrow][kc * 32 + quad * 8];

    f32x4 acc[4];
#pragma unroll
    for (int nt = 0; nt < 4; ++nt) acc[nt] = (f32x4){0.f, 0.f, 0.f, 0.f};

#pragma unroll
    for (int nt = 0; nt < 4; ++nt) {
        const int col = c0 + nt * 16 + lrow;
        const __bf16* wb = Wt + col * 128 + quad * 8;
#pragma unroll
        for (int kc = 0; kc < 4; ++kc) {
            bf16x8 bF = *(const bf16x8*)(wb + kc * 32);
            acc[nt] = __builtin_amdgcn_mfma_f32_16x16x32_bf16(aF[kc], bF, acc[nt], 0, 0, 0);
        }
    }

    // ---- Epilogue: C/D layout col=lane&15, row=quad*4+i; NT stores ----
#pragma unroll
    for (int nt = 0; nt < 4; ++nt) {
        const int col = c0 + nt * 16 + lrow;
        const float bv = bias[col];
#pragma unroll
        for (int i = 0; i < 4; ++i) {
            const int r = r0 + quad * 4 + i;
            float v = fmaxf(acc[nt][i] + bv, 0.f);
            __builtin_nontemporal_store(v, &out[(size_t)(rowbase + r) * 128 + col]);
        }
    }
}

// ---------------------------------------------------------------------------
extern "C" void kernel_launch(void* const* d_in, const int* in_sizes, int n_in,
                              void* d_out, int out_size, void* d_ws, size_t ws_size,
                              hipStream_t stream) {
    const float* atom = (const float*)d_in[0];
    const float* bond = (const float*)d_in[1];
    const int*   adj  = (const int*)d_in[2];
    const float* W    = (const float*)d_in[3];
    const float* bias = (const float*)d_in[4];
    float* out = (float*)d_out;

    char* ws = (char*)d_ws;
    float*  p  = (float*)ws;               // 16384 f32 = 64 KB
    __bf16* Wt = (__bf16*)(ws + 65536);    // 16384 bf16 = 32 KB

    hipLaunchKernelGGL(k_bond, dim3(260), dim3(256), 0, stream, bond, W, p, Wt);
    hipLaunchKernelGGL(k_main, dim3(512), dim3(256), 0, stream, atom, adj, p, Wt, bias, out);
}

// Round 8
// 101.750 us; speedup vs baseline: 1.1482x; 1.0033x over previous
//
#include <hip/hip_runtime.h>
#include <hip/hip_bf16.h>

#define EPS 1e-12f

typedef __bf16 bf16x8 __attribute__((ext_vector_type(8)));
typedef __bf16 bf16x4 __attribute__((ext_vector_type(4)));
typedef float  f32x4  __attribute__((ext_vector_type(4)));

// Problem constants: B=16, N=1024, M=12, F_atom=128, F_bond=32, F_out=128

// ---------------------------------------------------------------------------
// K1 blocks 0..255 : bond-norm chain -> p[row], 4 threads per row, NT loads.
//    p = (prod_m x_m) / d^12, d = max(sum_m x_m, EPS), x_m = 1/||bond_m||^2
// K1 blocks 256..259 : W (128x128 f32 [k][j]) -> Wt bf16 [j][k]
// ---------------------------------------------------------------------------
__global__ __launch_bounds__(256) void k_bond(const float* __restrict__ bond,
                                              const float* __restrict__ W,
                                              float* __restrict__ p_out,
                                              __bf16* __restrict__ Wt) {
    const int t = threadIdx.x;
    if (blockIdx.x < 256) {
        const int gtid = blockIdx.x * 256 + t;
        const int row  = gtid >> 2;      // 0..16383
        const int q    = gtid & 3;       // m = 3q..3q+2
        const float* base = bond + (size_t)row * 384 + q * 96;

        float x[3];
#pragma unroll
        for (int mm = 0; mm < 3; ++mm) {
            float s = 0.f;
#pragma unroll
            for (int j = 0; j < 8; ++j) {
                f32x4 v = __builtin_nontemporal_load((const f32x4*)(base + mm * 32 + j * 4));
                s = fmaf(v.x, v.x, s);
                s = fmaf(v.y, v.y, s);
                s = fmaf(v.z, v.z, s);
                s = fmaf(v.w, v.w, s);
            }
            x[mm] = 1.0f / s;            // (sqrt(s))^-2 == 1/s
        }
        float sum  = x[0] + x[1] + x[2];
        float prod = x[0] * x[1] * x[2];
        sum  += __shfl_xor(sum, 1);  prod *= __shfl_xor(prod, 1);
        sum  += __shfl_xor(sum, 2);  prod *= __shfl_xor(prod, 2);
        if (q == 0) {
            float d   = fmaxf(sum, EPS);
            float d2  = d * d, d3 = d2 * d, d6 = d3 * d3;
            p_out[row] = prod / (d6 * d6);   // prod(x/d) = prod(x)/d^12
        }
    } else {
        const int base = (blockIdx.x - 256) * 4096;
#pragma unroll
        for (int i = 0; i < 16; ++i) {
            int idx = base + t + 256 * i;
            int k = idx >> 7, j = idx & 127;
            Wt[j * 128 + k] = (__bf16)W[idx];
        }
    }
}

// ---------------------------------------------------------------------------
// K2: 64 rows/block (256 blocks) — halves the redundant per-block scale
// computation and dispatch count vs 32-row blocks. XCD swizzle: lower 3 bits
// of blk = XCD residue; each XCD serves 2 batches (1 MB atom working set,
// L2-resident).
// ---------------------------------------------------------------------------
__global__ __launch_bounds__(256) void k_main(const float* __restrict__ atom,
                                              const int* __restrict__ adj,
                                              const float* __restrict__ p,
                                              const __bf16* __restrict__ Wt,
                                              const float* __restrict__ bias,
                                              float* __restrict__ out) {
    __shared__ __bf16 uA[64][136];   // 17.4 KB; stride 136: 8B-aligned, 2-way banking (free)
    __shared__ float  sScale[64] __attribute__((aligned(16)));
    __shared__ int    sAdj[64 * 12];
    __shared__ float  red[4];

    const int t = threadIdx.x;
    // blk = xcd + 8*slot + 128*hi : b = xcd | hi<<3 (batches with same XCD residue),
    // slot 0..15 -> 64 rows each.
    const int blk = blockIdx.x;
    const int b   = (blk & 7) | (((blk >> 7) & 1) << 3);
    const int nlo = ((blk >> 3) & 15) * 64;
    const int rowbase = b * 1024 + nlo;

    for (int idx = t; idx < 64 * 12; idx += 256) sAdj[idx] = adj[rowbase * 12 + idx];

    // ---- Phase 0: scale (vectorized, immediate accumulation) ----
    // r[n] = max(sum_bb p[bb,n], EPS) / p[b,n];  scale = r / max(sum_n r, EPS)
    const int n0 = t * 4;                  // local n in [0,1024)
    f32x4 cs = {0.f, 0.f, 0.f, 0.f};
#pragma unroll
    for (int bb = 0; bb < 16; ++bb) cs += *(const f32x4*)(p + bb * 1024 + n0);
    f32x4 pb = *(const f32x4*)(p + b * 1024 + n0);   // L2-hot re-read
    f32x4 r4;
    r4.x = fmaxf(cs.x, EPS) / pb.x;
    r4.y = fmaxf(cs.y, EPS) / pb.y;
    r4.z = fmaxf(cs.z, EPS) / pb.z;
    r4.w = fmaxf(cs.w, EPS) / pb.w;
    float S_part = r4.x + r4.y + r4.z + r4.w;
#pragma unroll
    for (int off = 32; off >= 1; off >>= 1) S_part += __shfl_xor(S_part, off);
    if ((t & 63) == 0) red[t >> 6] = S_part;
    __syncthreads();
    const float invS = 1.0f / fmaxf(red[0] + red[1] + red[2] + red[3], EPS);
    if (n0 >= nlo && n0 < nlo + 64) *(f32x4*)&sScale[n0 - nlo] = r4 * invS;
    __syncthreads();

    // ---- Phase 1: float4 gather; u = (own + accn/12) * scale -> bf16 LDS ----
    {
        const int jc = (t & 31) * 4;       // 4 cols/thread
        const int rg = t >> 5;             // 8 rows in parallel
        const float* atomB = atom + (size_t)b * (1024 * 128);
#pragma unroll
        for (int i = 0; i < 8; ++i) {
            const int r = rg + i * 8;
            f32x4 a = {0.f, 0.f, 0.f, 0.f};
#pragma unroll
            for (int m = 0; m < 12; ++m) {
                int idx = sAdj[r * 12 + m];
                a += *(const f32x4*)(atomB + (size_t)idx * 128 + jc);
            }
            f32x4 own = *(const f32x4*)(atomB + (size_t)(nlo + r) * 128 + jc);
            f32x4 u = (own + a * (1.0f / 12.0f)) * sScale[r];
            bf16x4 ub;
            ub.x = (__bf16)u.x; ub.y = (__bf16)u.y; ub.z = (__bf16)u.z; ub.w = (__bf16)u.w;
            *(bf16x4*)&uA[r][jc] = ub;
        }
    }
    __syncthreads();

    // ---- Phase 2: wave w owns rows w*16..+15, all 128 cols (8 n-tiles) ----
    const int wave = t >> 6, lane = t & 63;
    const int r0 = wave * 16;
    const int quad = lane >> 4, lrow = lane & 15;

    bf16x8 aF[4];
#pragma unroll
    for (int kc = 0; kc < 4; ++kc)
        aF[kc] = *(const bf16x8*)&uA[r0 + lrow][kc * 32 + quad * 8];

    f32x4 acc[8];
#pragma unroll
    for (int nt = 0; nt < 8; ++nt) acc[nt] = (f32x4){0.f, 0.f, 0.f, 0.f};

#pragma unroll
    for (int nt = 0; nt < 8; ++nt) {
        const int col = nt * 16 + lrow;
        const __bf16* wb = Wt + col * 128 + quad * 8;
#pragma unroll
        for (int kc = 0; kc < 4; ++kc) {
            bf16x8 bF = *(const bf16x8*)(wb + kc * 32);
            acc[nt] = __builtin_amdgcn_mfma_f32_16x16x32_bf16(aF[kc], bF, acc[nt], 0, 0, 0);
        }
    }

    // ---- Epilogue: C/D layout col=lane&15, row=quad*4+i; NT stores ----
#pragma unroll
    for (int nt = 0; nt < 8; ++nt) {
        const int col = nt * 16 + lrow;
        const float bv = bias[col];
#pragma unroll
        for (int i = 0; i < 4; ++i) {
            const int r = r0 + quad * 4 + i;
            float v = fmaxf(acc[nt][i] + bv, 0.f);
            __builtin_nontemporal_store(v, &out[(size_t)(rowbase + r) * 128 + col]);
        }
    }
}

// ---------------------------------------------------------------------------
extern "C" void kernel_launch(void* const* d_in, const int* in_sizes, int n_in,
                              void* d_out, int out_size, void* d_ws, size_t ws_size,
                              hipStream_t stream) {
    const float* atom = (const float*)d_in[0];
    const float* bond = (const float*)d_in[1];
    const int*   adj  = (const int*)d_in[2];
    const float* W    = (const float*)d_in[3];
    const float* bias = (const float*)d_in[4];
    float* out = (float*)d_out;

    char* ws = (char*)d_ws;
    float*  p  = (float*)ws;               // 16384 f32 = 64 KB
    __bf16* Wt = (__bf16*)(ws + 65536);    // 16384 bf16 = 32 KB

    hipLaunchKernelGGL(k_bond, dim3(260), dim3(256), 0, stream, bond, W, p, Wt);
    hipLaunchKernelGGL(k_main, dim3(256), dim3(256), 0, stream, atom, adj, p, Wt, bias, out);
}